// Round 1
// 163.343 us; speedup vs baseline: 1.0007x; 1.0007x over previous
//
#include <hip/hip_runtime.h>

#define OUT 7
#define NB 4        // batch
#define NC 256      // channels
#define NN 256      // rois per image
#define EPR (NC * OUT * OUT)   // 12544 elements per roi

typedef float nfloat4 __attribute__((ext_vector_type(4)));
typedef unsigned short nushort4 __attribute__((ext_vector_type(4)));
typedef unsigned short nushort2 __attribute__((ext_vector_type(2)));

__device__ inline unsigned short f2bf(float f) {
    unsigned u = __builtin_bit_cast(unsigned, f);
    u += 0x7FFFu + ((u >> 16) & 1u);          // round-to-nearest-even
    return (unsigned short)(u >> 16);
}

__device__ inline float bf2f(unsigned short s) {
    return __builtin_bit_cast(float, (unsigned)s << 16);
}

// ---------------------------------------------------------------------------
// Kernel 1: fused transpose of ALL 5 FPN levels [B][C][P] -> bf16 [B][P][C].
// Each block: 32 p x 128 c macro-tile (4 c-tiles sequentially through one LDS
// tile). Nontemporal fp32 loads (read-once), cached bf16 stores (re-read by
// the gather). 5456 blocks. Streaming, no inter-block reuse -> no swizzle.
// ---------------------------------------------------------------------------
__global__ __launch_bounds__(256) void transpose_all(
    const float* __restrict__ f0, const float* __restrict__ f1,
    const float* __restrict__ f2, const float* __restrict__ f3,
    const float* __restrict__ f4, unsigned short* __restrict__ T)
{
    __shared__ float tile[32][33];
    const int bx = blockIdx.x;

    const float* in; unsigned short* outp; int P, t, shp;
    if (bx < 4096)      { in = f0; outp = T;            P = 16384; t = bx;        shp = 9; }
    else if (bx < 5120) { in = f1; outp = T + 16777216; P = 4096;  t = bx - 4096; shp = 7; }
    else if (bx < 5376) { in = f2; outp = T + 20971520; P = 1024;  t = bx - 5120; shp = 5; }
    else if (bx < 5440) { in = f3; outp = T + 22020096; P = 256;   t = bx - 5376; shp = 3; }
    else                { in = f4; outp = T + 22282240; P = 64;    t = bx - 5440; shp = 1; }

    const int pt   = t & ((1 << shp) - 1);
    const int rest = t >> shp;
    const int cm   = rest & 1;      // c-macro: 0 -> ch 0..127, 1 -> 128..255
    const int b    = rest >> 1;
    const int p0   = pt << 5;
    const int tx   = threadIdx.x & 7;
    const int ty   = threadIdx.x >> 3;

    #pragma unroll
    for (int ct = 0; ct < 4; ++ct) {
        const int c0 = (cm << 7) + (ct << 5);
        const float* src = in + ((size_t)((b << 8) + c0 + ty)) * P + p0 + (tx << 2);
        nfloat4 v = __builtin_nontemporal_load((const nfloat4*)src);
        tile[ty][tx * 4 + 0] = v.x;
        tile[ty][tx * 4 + 1] = v.y;
        tile[ty][tx * 4 + 2] = v.z;
        tile[ty][tx * 4 + 3] = v.w;
        __syncthreads();

        nushort4 w;
        w.x = f2bf(tile[4 * tx + 0][ty]);
        w.y = f2bf(tile[4 * tx + 1][ty]);
        w.z = f2bf(tile[4 * tx + 2][ty]);
        w.w = f2bf(tile[4 * tx + 3][ty]);
        unsigned short* dst = outp + ((size_t)b * P + p0 + ty) * NC + c0 + (tx << 2);
        *(nushort4*)dst = w;
        __syncthreads();
    }
}

// ---------------------------------------------------------------------------
// Kernel 2: gather. 2048 blocks. XCD-aware bijective swizzle (grid%8==0):
// hardware round-robins dispatch index h -> XCD h&7, so logical block
// j = (h&7)*256 + (h>>3) gives XCD x the contiguous run [x*256, x*256+256)
// = 128 rois of ONE image b = x>>1. Per-XCD gather footprint drops from the
// full 44.7 MB transposed buffer to ~10.5 MB, of which the lvl1(2MB) and
// lvl2(0.5MB) per-image slices are L2-resident (4 MiB/XCD) -> the majority
// of rois gather from L2 instead of Infinity Cache.
// Logical j>>1 = roi, j&1 = 128-channel half. Lane owns 2 consecutive
// channels (ushort2 bf16 -> 256B coalesced wave-loads on disjoint
// half-lines). Wave q handles positions q*13+i (i=0..12, clamp 48 =
// same-thread benign rewrite). 2-stage pipeline: next position's 16 loads
// in flight during current compute; weights recomputed from LDS in the
// compute stage to keep VGPR < 102.
// LDS 25 KB -> 5 blocks/CU with launch_bounds(256,5).
// ---------------------------------------------------------------------------
__global__ __launch_bounds__(256, 5) void msroi_fast(
    const unsigned short* __restrict__ T, const float* __restrict__ rois,
    float* __restrict__ out)
{
    // bijective XCD swizzle: grid = 2048 = 8 * 256
    const int j     = ((blockIdx.x & 7) << 8) + (blockIdx.x >> 3);
    const int roi   = j >> 1;
    const int chunk = j & 1;
    const int tid   = threadIdx.x;

    __shared__ float s_wy[2][14];   // [0]=vy*(1-ly), [1]=vy*ly
    __shared__ float s_wx[2][14];   // [0]=vx*(1-lx), [1]=vx*lx
    __shared__ int   s_yr[2][14];   // y0*W, y1*W
    __shared__ int   s_xc[2][14];   // x0, x1
    __shared__ int   s_lvl;
    __shared__ __align__(16) float s_out[128 * 49];   // 25088 B

    if (tid < 28) {
        const float rx1 = rois[roi * 4 + 0];
        const float ry1 = rois[roi * 4 + 1];
        const float rx2 = rois[roi * 4 + 2];
        const float ry2 = rois[roi * 4 + 3];

        float area = (rx2 - rx1) * (ry2 - ry1);
        float lf = floorf(4.0f + log2f(sqrtf(area) / 224.0f + 1e-6f));
        lf = fminf(fmaxf(lf, 2.0f), 6.0f);
        int lvl = (int)lf - 2;
        if (tid == 0) s_lvl = lvl;

        float scale = 1.0f / (float)(4 << lvl);
        int   W     = 128 >> lvl;

        float x1 = rx1 * scale, y1 = ry1 * scale;
        float x2 = rx2 * scale, y2 = ry2 * scale;
        float rw = fmaxf(x2 - x1, 1.0f);
        float rh = fmaxf(y2 - y1, 1.0f);
        float bw = rw / (float)OUT;
        float bh = rh / (float)OUT;

        bool isx = (tid >= 14);
        int  g   = isx ? tid - 14 : tid;
        float gv = ((float)g + 0.5f) * 0.5f;
        float p  = isx ? (x1 + gv * bw) : (y1 + gv * bh);

        float v = (p >= -1.0f && p <= (float)W) ? 1.0f : 0.0f;
        float pc  = fminf(fmaxf(p, 0.0f), (float)(W - 1));
        float p0f = floorf(pc);
        int   p0  = (int)p0f;
        int   p1  = min(p0 + 1, W - 1);
        float l   = pc - p0f;

        if (isx) {
            s_xc[0][g] = p0; s_xc[1][g] = p1;
            s_wx[0][g] = v * (1.0f - l); s_wx[1][g] = v * l;
        } else {
            s_yr[0][g] = p0 * W; s_yr[1][g] = p1 * W;
            s_wy[0][g] = v * (1.0f - l); s_wy[1][g] = v * l;
        }
    }
    __syncthreads();

    const int lvl = s_lvl;
    const int W   = 128 >> lvl;
    const int POS = W * W;
    const int off_tab[5] = {0, 16777216, 20971520, 22020096, 22282240};
    const int b    = roi >> 8;
    const int q    = tid >> 6;          // wave id 0..3
    const int cl   = (tid & 63) << 1;   // local channel 0..126 (2 per lane)
    const unsigned short* base =
        T + (size_t)off_tab[lvl] + (size_t)b * POS * NC + (chunk << 7) + cl;

    // 16 corner element-offsets for one output position (addresses only)
    auto make_off = [&](int p, int* off) {
        const int oy = p / 7;
        const int ox = p - oy * 7;
        const int R[4] = { s_yr[0][2 * oy],     s_yr[1][2 * oy],
                           s_yr[0][2 * oy + 1], s_yr[1][2 * oy + 1] };
        const int C[4] = { s_xc[0][2 * ox],     s_xc[1][2 * ox],
                           s_xc[0][2 * ox + 1], s_xc[1][2 * ox + 1] };
        #pragma unroll
        for (int a = 0; a < 4; ++a)
            #pragma unroll
            for (int c2 = 0; c2 < 4; ++c2)
                off[a * 4 + c2] = R[a] + C[c2];
    };

    int p_cur = min(q * 13, 48);
    int offA[16];
    nushort2 L[16], M[16];
    make_off(p_cur, offA);
    #pragma unroll
    for (int k = 0; k < 16; ++k)
        L[k] = *(const nushort2*)&base[(size_t)offA[k] << 8];

    #pragma unroll
    for (int i = 0; i < 13; ++i) {
        const int p_nxt = min(q * 13 + i + 1, 48);
        if (i < 12) {
            int offB[16];
            make_off(p_nxt, offB);
            #pragma unroll
            for (int k = 0; k < 16; ++k)
                M[k] = *(const nushort2*)&base[(size_t)offB[k] << 8];
        }

        // weights for current position (recomputed from LDS -> low VGPR)
        const int oy = p_cur / 7;
        const int ox = p_cur - oy * 7;
        const float WY[4] = { s_wy[0][2 * oy],     s_wy[1][2 * oy],
                              s_wy[0][2 * oy + 1], s_wy[1][2 * oy + 1] };
        const float WX[4] = { s_wx[0][2 * ox],     s_wx[1][2 * ox],
                              s_wx[0][2 * ox + 1], s_wx[1][2 * ox + 1] };

        float a0 = 0.0f, a1 = 0.0f;
        #pragma unroll
        for (int k = 0; k < 16; ++k) {
            const float w = WY[k >> 2] * WX[k & 3];
            a0 += w * bf2f(L[k].x);
            a1 += w * bf2f(L[k].y);
        }

        s_out[(cl + 0) * 49 + p_cur] = a0 * 0.25f;
        s_out[(cl + 1) * 49 + p_cur] = a1 * 0.25f;

        #pragma unroll
        for (int k = 0; k < 16; ++k) L[k] = M[k];
        p_cur = p_nxt;
    }
    __syncthreads();

    // cooperative coalesced nontemporal store: 6272 floats = 1568 float4
    float* ob = out + (size_t)roi * EPR + (chunk << 7) * 49;
    #pragma unroll
    for (int k = 0; k < 6; ++k) {
        const int f = (tid + (k << 8)) << 2;
        nfloat4 v = *(const nfloat4*)&s_out[f];
        __builtin_nontemporal_store(v, (nfloat4*)&ob[f]);
    }
    if (tid < 32) {
        const int f = (tid + 1536) << 2;
        nfloat4 v = *(const nfloat4*)&s_out[f];
        __builtin_nontemporal_store(v, (nfloat4*)&ob[f]);
    }
}

// ---------------------------------------------------------------------------
// Fallback (round-2 kernel, fp32 direct) if workspace is too small
// ---------------------------------------------------------------------------
__global__ __launch_bounds__(256) void msroi_kernel(
    const float* __restrict__ f0, const float* __restrict__ f1,
    const float* __restrict__ f2, const float* __restrict__ f3,
    const float* __restrict__ f4, const float* __restrict__ rois,
    float* __restrict__ out)
{
    const int roi = blockIdx.y;
    const int tid = threadIdx.x;

    __shared__ float s_wyt[14], s_wyb[14];
    __shared__ float s_wxl[14], s_wxr[14];
    __shared__ int   s_oy0[14], s_oy1[14];
    __shared__ int   s_x0[14],  s_x1[14];
    __shared__ int   s_lvl;

    if (tid < 28) {
        const float rx1 = rois[roi * 4 + 0];
        const float ry1 = rois[roi * 4 + 1];
        const float rx2 = rois[roi * 4 + 2];
        const float ry2 = rois[roi * 4 + 3];

        float area = (rx2 - rx1) * (ry2 - ry1);
        float lf = floorf(4.0f + log2f(sqrtf(area) / 224.0f + 1e-6f));
        lf = fminf(fmaxf(lf, 2.0f), 6.0f);
        int lvl = (int)lf - 2;
        if (tid == 0) s_lvl = lvl;

        float scale = 1.0f / (float)(4 << lvl);
        int   HW    = 128 >> lvl;

        float x1 = rx1 * scale, y1 = ry1 * scale;
        float x2 = rx2 * scale, y2 = ry2 * scale;
        float rw = fmaxf(x2 - x1, 1.0f);
        float rh = fmaxf(y2 - y1, 1.0f);
        float bw = rw / (float)OUT;
        float bh = rh / (float)OUT;

        bool isx = (tid >= 14);
        int  g   = isx ? tid - 14 : tid;
        float gv = ((float)g + 0.5f) * 0.5f;
        float p  = isx ? (x1 + gv * bw) : (y1 + gv * bh);

        float v = (p >= -1.0f && p <= (float)HW) ? 1.0f : 0.0f;
        float pc  = fminf(fmaxf(p, 0.0f), (float)(HW - 1));
        float p0f = floorf(pc);
        int   p0  = (int)p0f;
        int   p1  = min(p0 + 1, HW - 1);
        float l   = pc - p0f;

        if (isx) {
            s_x0[g] = p0; s_x1[g] = p1;
            s_wxl[g] = v * (1.0f - l); s_wxr[g] = v * l;
        } else {
            s_oy0[g] = p0 * HW; s_oy1[g] = p1 * HW;
            s_wyt[g] = v * (1.0f - l); s_wyb[g] = v * l;
        }
    }
    __syncthreads();

    const int lvl = s_lvl;
    const int HW  = 128 >> lvl;
    const int HW2 = HW * HW;
    const float* f = (lvl == 0) ? f0 : (lvl == 1) ? f1 : (lvl == 2) ? f2
                     : (lvl == 3) ? f3 : f4;
    const int b = roi >> 8;

    const int e0 = blockIdx.x * 512 + tid;

    float acc[2];
    #pragma unroll
    for (int k = 0; k < 2; ++k) {
        const int e  = e0 + k * 256;
        const int ec = (e < EPR) ? e : 0;
        const int c  = ec / 49;
        const int s  = ec - 49 * c;
        const int oy = s / 7;
        const int ox = s - 7 * oy;

        const float* fp = f + (size_t)(b * NC + c) * (size_t)HW2;

        float a = 0.0f;
        #pragma unroll
        for (int iy = 0; iy < 2; ++iy) {
            const int gy = oy * 2 + iy;
            const float wt = s_wyt[gy], wb = s_wyb[gy];
            const int   o0 = s_oy0[gy], o1 = s_oy1[gy];
            #pragma unroll
            for (int ix = 0; ix < 2; ++ix) {
                const int gx = ox * 2 + ix;
                const float wl = s_wxl[gx], wr = s_wxr[gx];
                const int   x0 = s_x0[gx],  x1i = s_x1[gx];
                const float v00 = fp[o0 + x0];
                const float v01 = fp[o0 + x1i];
                const float v10 = fp[o1 + x0];
                const float v11 = fp[o1 + x1i];
                a += (wt * wl) * v00 + (wt * wr) * v01
                   + (wb * wl) * v10 + (wb * wr) * v11;
            }
        }
        acc[k] = a * 0.25f;
    }

    #pragma unroll
    for (int k = 0; k < 2; ++k) {
        const int e = e0 + k * 256;
        if (e < EPR)
            __builtin_nontemporal_store(acc[k], &out[(size_t)roi * EPR + e]);
    }
}

extern "C" void kernel_launch(void* const* d_in, const int* in_sizes, int n_in,
                              void* d_out, int out_size, void* d_ws, size_t ws_size,
                              hipStream_t stream) {
    const float* f0   = (const float*)d_in[0];
    const float* f1   = (const float*)d_in[1];
    const float* f2   = (const float*)d_in[2];
    const float* f3   = (const float*)d_in[3];
    const float* f4   = (const float*)d_in[4];
    const float* rois = (const float*)d_in[5];
    float* out = (float*)d_out;

    const size_t need = 22347776ull * 2ull;   // 44.7 MB bf16 transposed features
    if (ws_size >= need) {
        unsigned short* T = (unsigned short*)d_ws;
        transpose_all<<<dim3(5456), dim3(256), 0, stream>>>(f0, f1, f2, f3, f4, T);
        msroi_fast<<<dim3(NB * NN * 2), dim3(256), 0, stream>>>(T, rois, out);
    } else {
        dim3 grid((EPR + 511) / 512, NB * NN);
        dim3 block(256);
        msroi_kernel<<<grid, block, 0, stream>>>(f0, f1, f2, f3, f4, rois, out);
    }
}